// Round 9
// baseline (152.956 us; speedup 1.0000x reference)
//
#include <hip/hip_runtime.h>

// B=8, T=2048, C=1024, H=64.  Reference: softmax over QUERY axis (dim=1),
// no 1/sqrt(d) scale.  out[t,h] = sum_{s<=t} exp(q_t.k_s)/D_s * v[s,h],
// D_s = sum_{t>=s} exp(q_t.k_s).
//
// qkv GEMM: 2-term split (exact-A x bf16-W), counted-vmcnt DMA pipeline (r20).
// Q/K stored hi+lo for 3-term QK dots; V, P plain bf16.
// Round-21: swapped QK MFMA (row=s,col=t) + swizzled-LDS transpose to A-frags.
// Round-22: ELIMINATE P MATERIALIZATION (67 MB write + 67 MB read).  QK^T is
// only ~13 GFLOP — recomputing it is cheaper than round-tripping P.
//   stats_d: D only (r21 stats minus P store/LDS/barriers).
//   out_fused: per (t-tile, s-chunk): recompute swapped QK^T (K per js, Q
//   hoisted), exp+mask, swizzled-LDS transpose to P A-frags, PV MFMA with
//   pre-scaled V.  P never leaves LDS.  Numerics bit-identical to r21.

typedef __attribute__((ext_vector_type(8))) short bf16x8;
typedef __attribute__((ext_vector_type(4))) float f32x4;
typedef unsigned short u16;

#define MFMA(a, b, c) __builtin_amdgcn_mfma_f32_16x16x32_bf16((a), (b), (c), 0, 0, 0)

__device__ __forceinline__ u16 f2bf(float x) {           // RNE fp32 -> bf16
    unsigned u = __float_as_uint(x);
    u += 0x7fff + ((u >> 16) & 1);
    return (u16)(u >> 16);
}
__device__ __forceinline__ float bf2f(u16 h) {
    return __uint_as_float(((unsigned)h) << 16);
}

// trunc-split 8 fp32 -> hi bf16x8 + lo bf16x8 (exact residual).  ~3 VALU/flt.
__device__ __forceinline__ void split8(const f32x4 x0, const f32x4 x1,
                                       bf16x8* hv, bf16x8* lv)
{
    const float f[8] = {x0[0], x0[1], x0[2], x0[3], x1[0], x1[1], x1[2], x1[3]};
    union { unsigned u[4]; bf16x8 v; } H, L;
    #pragma unroll
    for (int j = 0; j < 4; ++j) {
        const unsigned u0 = __float_as_uint(f[2 * j]);
        const unsigned u1 = __float_as_uint(f[2 * j + 1]);
        H.u[j] = __builtin_amdgcn_perm(u1, u0, 0x07060302);   // top16 of each
        const float l0 = f[2 * j]     - __uint_as_float(u0 & 0xffff0000u);
        const float l1 = f[2 * j + 1] - __uint_as_float(u1 & 0xffff0000u);
        L.u[j] = __builtin_amdgcn_perm(__float_as_uint(l1), __float_as_uint(l0),
                                       0x07060302);
    }
    *hv = H.v;
    *lv = L.v;
}

typedef const __attribute__((address_space(1))) void* gas_p;
typedef __attribute__((address_space(3))) void* las_p;

// ws byte offsets
#define WH_OFF  0u
#define FQH_OFF (WH_OFF + 2u*192u*1024u*2u)
#define FQL_OFF (FQH_OFF + 2u*1024u*1024u)
#define FKH_OFF (FQL_OFF + 2u*1024u*1024u)
#define FKL_OFF (FKH_OFF + 2u*1024u*1024u)
#define VF_OFF  (FKL_OFF + 2u*1024u*1024u)
#define DD_OFF  (VF_OFF + 2u*1024u*1024u)          // fp32 [B][T] = 64 KB

// ---------------------------------------------------------------------------
// W -> fragment-coalesced bf16 (RNE).  Chunk kc (32 K-elems) of col-block
// nblk lives at nblk*16384 + kc*512 u16.
// ---------------------------------------------------------------------------
__global__ __launch_bounds__(128) void wsplit_kernel(
    const float* __restrict__ Wk, const float* __restrict__ Wq,
    const float* __restrict__ Wv, u16* __restrict__ FWH)
{
    const int n = blockIdx.x;                 // 0..191
    const int nblk = n >> 4, lr = n & 15;
    const float* src = (n < 64) ? (Wq + (long)n * 1024)
                     : (n < 128) ? (Wk + (long)(n - 64) * 1024)
                                 : (Wv + (long)(n - 128) * 1024);
    const int f = threadIdx.x;                // 0..127 fragment id
    const int kc = f >> 2, q = f & 3;
    const float4 f0 = *(const float4*)&src[kc * 32 + q * 8];
    const float4 f1 = *(const float4*)&src[kc * 32 + q * 8 + 4];
    const float vs[8] = {f0.x, f0.y, f0.z, f0.w, f1.x, f1.y, f1.z, f1.w};
    bf16x8 hv;
    #pragma unroll
    for (int j = 0; j < 8; ++j) hv[j] = (short)f2bf(vs[j]);
    const long o = ((long)(nblk * 32 + kc) * 64 + q * 16 + lr) * 8;
    *(bf16x8*)&FWH[o] = hv;
}

// ---------------------------------------------------------------------------
// qkv (r20 verbatim).  Counted-vmcnt DMA pipeline, 2-term split, phase K=64,
// 3 stages x 40 KB LDS, 5 DMA/wave/phase, boundary vmcnt(5) + bare s_barrier.
// ---------------------------------------------------------------------------
__global__ __launch_bounds__(512, 2) void qkv_kernel(
    const float* __restrict__ idx, const u16* __restrict__ FWH,
    u16* __restrict__ FQH, u16* __restrict__ FQL,
    u16* __restrict__ FKH, u16* __restrict__ FKL, u16* __restrict__ VF)
{
    __shared__ __align__(16) char smem[3][40960];   // A 16KB + FWH 24KB
    const int tid = threadIdx.x;
    const int w = tid >> 6, lr = tid & 15, quad = (tid >> 4) & 3;
    const int lane = tid & 63;
    const int r0 = blockIdx.x * 64;
    const int b = r0 >> 11, t0 = r0 & 2047;
    const int m0 = (w & 1) * 32;
    const int nbb = (w >> 1) * 3;

    const float* asrc[2];
    int adst[2];
    #pragma unroll
    for (int j = 0; j < 2; ++j) {
        const int s = w * 2 + j;
        const int row = s * 4 + (lane >> 4);
        const int lc = (lane & 15) ^ (row & 7);
        asrc[j] = idx + (long)(r0 + row) * 1024 + lc * 4;
        adst[j] = s * 1024;
    }
    const u16* fsrc[3];
    int fdst[3];
    #pragma unroll
    for (int j = 0; j < 3; ++j) {
        const int seg = w * 3 + j;
        const int nblk = seg >> 1, kcl = seg & 1;
        fsrc[j] = FWH + (long)nblk * 16384 + kcl * 512 + lane * 8;
        fdst[j] = 16384 + seg * 1024;
    }

#define ISSUE(PH)                                                             \
    {                                                                         \
        const int nb_ = (PH) % 3;                                             \
        _Pragma("unroll")                                                     \
        for (int j = 0; j < 2; ++j)                                           \
            __builtin_amdgcn_global_load_lds((gas_p)(asrc[j] + (PH) * 64),    \
                (las_p)(smem[nb_] + adst[j]), 16, 0, 0);                      \
        _Pragma("unroll")                                                     \
        for (int j = 0; j < 3; ++j)                                           \
            __builtin_amdgcn_global_load_lds((gas_p)(fsrc[j] + (long)(PH) * 1024), \
                (las_p)(smem[nb_] + fdst[j]), 16, 0, 0);                      \
    }

#define COMPUTE(PH)                                                           \
    {                                                                         \
        const int nb_ = (PH) % 3;                                             \
        const float* A_ = (const float*)smem[nb_];                            \
        const u16* F_ = (const u16*)(smem[nb_] + 16384);                      \
        _Pragma("unroll")                                                     \
        for (int kc = 0; kc < 2; ++kc) {                                      \
            bf16x8 AH[2], AL[2];                                              \
            _Pragma("unroll")                                                 \
            for (int mi = 0; mi < 2; ++mi) {                                  \
                const int R = m0 + mi * 16 + lr;                              \
                const int c0 = (kc * 8 + quad * 2) ^ (lr & 7);                \
                const f32x4 x0 = *(const f32x4*)&A_[R * 64 + c0 * 4];         \
                const f32x4 x1 = *(const f32x4*)&A_[R * 64 + (c0 ^ 1) * 4];   \
                split8(x0, x1, &AH[mi], &AL[mi]);                             \
            }                                                                 \
            _Pragma("unroll")                                                 \
            for (int nf = 0; nf < 3; ++nf) {                                  \
                const int sb = (((nbb + nf) * 2 + kc)) * 512 + lane * 8;      \
                const bf16x8 bh = *(const bf16x8*)&F_[sb];                    \
                _Pragma("unroll")                                             \
                for (int mi = 0; mi < 2; ++mi) {                              \
                    f32x4 c = acc[mi][nf];                                    \
                    c = MFMA(AH[mi], bh, c);                                  \
                    c = MFMA(AL[mi], bh, c);                                  \
                    acc[mi][nf] = c;                                          \
                }                                                             \
            }                                                                 \
        }                                                                     \
    }

#define WAITV(N)                                                              \
    asm volatile("s_waitcnt vmcnt(" #N ")" ::: "memory");                     \
    __builtin_amdgcn_sched_barrier(0);                                        \
    __builtin_amdgcn_s_barrier();

    f32x4 acc[2][3] = {};

    ISSUE(0); ISSUE(1);
    WAITV(5)

    for (int ph = 0; ph < 14; ++ph) {
        ISSUE(ph + 2);
        __builtin_amdgcn_sched_barrier(0);
        COMPUTE(ph);
        WAITV(5)
    }
    COMPUTE(14);
    WAITV(0)
    COMPUTE(15);

#undef WAITV
#undef COMPUTE
#undef ISSUE

    #pragma unroll
    for (int mi = 0; mi < 2; ++mi) {
        const int tb = t0 + m0 + mi * 16 + quad * 4;
        const int tblk = (t0 + m0 + mi * 16) >> 4;
        #pragma unroll
        for (int nf = 0; nf < 3; ++nf) {
            const int n = (nbb + nf) * 16 + lr;
            const f32x4 a = acc[mi][nf];
            if (n < 128) {
                u16* Hd = (n < 64) ? FQH : FKH;
                u16* Ld = (n < 64) ? FQL : FKL;
                const int h = n & 63;
                const int kc = h >> 5;
                const int lsub = 16 * ((h & 31) >> 3);
                const long base = ((long)(b * 128 + tblk) * 2 + kc) * 512 + (h & 7);
                #pragma unroll
                for (int r = 0; r < 4; ++r) {
                    const float v = a[r];
                    const u16 hi = f2bf(v);
                    const u16 lo = f2bf(v - bf2f(hi));
                    const long o = base + (long)(quad * 4 + r + lsub) * 8;
                    Hd[o] = hi; Ld[o] = lo;
                }
            } else {
                const int h = n - 128;
                const int hblk = h >> 4;
                #pragma unroll
                for (int r = 0; r < 4; ++r) {
                    const int t = tb + r;
                    const long o = ((long)(b * 4 + hblk) * 64 + (t >> 5)) * 512
                                 + (long)(16 * ((t & 31) >> 3) + (h & 15)) * 8 + (t & 7);
                    VF[o] = f2bf(a[r]);
                }
            }
        }
    }
}

// ---------------------------------------------------------------------------
// stats_d: D_s = sum_{t>=s} exp(q_t.k_s) ONLY (no P store).  Swapped MFMA
// (K as A, Q as B): thread holds s = s0+sf*16+quad*4+r, t = jt*64+w*16+lr.
// Grid (144, B): s-tile i, t-chunk x (<=4 t-tiles); atomicAdd partials.
// ---------------------------------------------------------------------------
__global__ __launch_bounds__(256, 4) void stats_kernel(
    const u16* __restrict__ FQH, const u16* __restrict__ FQL,
    const u16* __restrict__ FKH, const u16* __restrict__ FKL,
    float* __restrict__ D)
{
    __shared__ float red[4][64];
    const int tid = threadIdx.x;
    const int w = tid >> 6, lr = tid & 15, quad = (tid >> 4) & 3;
    const int lane = tid & 63;
    const int b = blockIdx.y;
    int x = blockIdx.x, i = 0;
    for (;;) { const int nc = (35 - i) >> 2; if (x < nc) break; x -= nc; ++i; }
    const int s0 = i * 64;
    const int jt0 = i + 4 * x, jt1 = min(jt0 + 4, 32);

    bf16x8 KH[4][2], KL[4][2];
    #pragma unroll
    for (int sf = 0; sf < 4; ++sf) {
        const long kb = ((long)(b * 128 + i * 4 + sf) * 2) * 512 + lane * 8;
        KH[sf][0] = *(const bf16x8*)&FKH[kb];
        KH[sf][1] = *(const bf16x8*)&FKH[kb + 512];
        KL[sf][0] = *(const bf16x8*)&FKL[kb];
        KL[sf][1] = *(const bf16x8*)&FKL[kb + 512];
    }

    float dsum[4][4] = {};
    for (int jt = jt0; jt < jt1; ++jt) {
        const long qb = ((long)(b * 128 + jt * 4 + w) * 2) * 512 + lane * 8;
        const bf16x8 qh0 = *(const bf16x8*)&FQH[qb];
        const bf16x8 qh1 = *(const bf16x8*)&FQH[qb + 512];
        const bf16x8 ql0 = *(const bf16x8*)&FQL[qb];
        const bf16x8 ql1 = *(const bf16x8*)&FQL[qb + 512];
        const bool diag = (jt == i);
        const int t_sub = w * 16 + lr;
        #pragma unroll
        for (int sf = 0; sf < 4; ++sf) {
            f32x4 cc = {};
            cc = MFMA(KH[sf][0], qh0, cc);
            cc = MFMA(KH[sf][0], ql0, cc);
            cc = MFMA(KL[sf][0], qh0, cc);
            cc = MFMA(KH[sf][1], qh1, cc);
            cc = MFMA(KH[sf][1], ql1, cc);
            cc = MFMA(KL[sf][1], qh1, cc);
            #pragma unroll
            for (int r = 0; r < 4; ++r) {
                float ev = __expf(cc[r]);
                if (diag && (t_sub < sf * 16 + quad * 4 + r)) ev = 0.f;
                dsum[sf][r] += ev;
            }
        }
    }

    #pragma unroll
    for (int sf = 0; sf < 4; ++sf)
        #pragma unroll
        for (int r = 0; r < 4; ++r) {
            float v = dsum[sf][r];
            v += __shfl_xor(v, 1);
            v += __shfl_xor(v, 2);
            v += __shfl_xor(v, 4);
            v += __shfl_xor(v, 8);
            dsum[sf][r] = v;
        }
    if (lr == 0) {
        #pragma unroll
        for (int sf = 0; sf < 4; ++sf)
            #pragma unroll
            for (int r = 0; r < 4; ++r)
                red[w][sf * 16 + quad * 4 + r] = dsum[sf][r];
    }
    __syncthreads();
    if (tid < 64)
        atomicAdd(&D[b * 2048 + s0 + tid],
                  red[0][tid] + red[1][tid] + red[2][tid] + red[3][tid]);
}

// ---------------------------------------------------------------------------
// vscale: VF (B-fragment layout) *= 1/D[s].
// ---------------------------------------------------------------------------
__global__ __launch_bounds__(256) void vscale_kernel(
    u16* __restrict__ VF, const float* __restrict__ D)
{
    const int g = blockIdx.x * 256 + threadIdx.x;   // 131072 threads x 8 u16
    const long e = (long)g * 8;
    const int lane = (int)((e >> 3) & 63);
    const int kc   = (int)((e >> 9) & 63);
    const int b    = (int)(e >> 17);
    const int s = kc * 32 + (lane >> 4) * 8;
    const float4 d0 = *(const float4*)&D[b * 2048 + s];
    const float4 d1 = *(const float4*)&D[b * 2048 + s + 4];
    const float dv[8] = {d0.x, d0.y, d0.z, d0.w, d1.x, d1.y, d1.z, d1.w};
    bf16x8 vv = *(bf16x8*)&VF[e];
    bf16x8 ov;
    #pragma unroll
    for (int j = 0; j < 8; ++j)
        ov[j] = (short)f2bf(bf2f((u16)vv[j]) / dv[j]);
    *(bf16x8*)&VF[e] = ov;
}

// ---------------------------------------------------------------------------
// out_fused: per (t-tile i, s-chunk): recompute swapped QK^T (K per js as
// A-operand, Q hoisted as B), exp+causal mask, pack quartets -> swizzled
// 64x64 LDS tile, barrier, read back P A-frags (ds_read_b128), PV MFMA with
// pre-scaled V.  P never touches global.  Epilogue: plain store (i<8) or
// atomicAdd.  Grid (80, B): t-tile i, s-chunk x (<=8 s-tiles).
// ---------------------------------------------------------------------------
__global__ __launch_bounds__(256, 2) void out_kernel(
    const u16* __restrict__ FQH, const u16* __restrict__ FQL,
    const u16* __restrict__ FKH, const u16* __restrict__ FKL,
    const u16* __restrict__ VF, float* __restrict__ out)
{
    __shared__ __align__(16) u16 p_l[64 * 64];     // swizzled [t_sub][s_sub]
    const int tid = threadIdx.x;
    const int w = tid >> 6, lr = tid & 15, quad = (tid >> 4) & 3;
    const int lane = tid & 63;
    const int b = blockIdx.y;
    int x = blockIdx.x, i = 0;
    for (;;) { const int nc = (i + 8) >> 3; if (x < nc) break; x -= nc; ++i; }
    const int t0 = i * 64;
    const int js0 = 8 * x, js1 = min(8 * x + 8, i + 1);

    // Q frags hoisted (B-operand, cols t = this wave's t-subtile w of tile i)
    const long qb = ((long)(b * 128 + i * 4 + w) * 2) * 512 + lane * 8;
    const bf16x8 qh0 = *(const bf16x8*)&FQH[qb];
    const bf16x8 qh1 = *(const bf16x8*)&FQH[qb + 512];
    const bf16x8 ql0 = *(const bf16x8*)&FQL[qb];
    const bf16x8 ql1 = *(const bf16x8*)&FQL[qb + 512];
    const int t_sub = w * 16 + lr;

    f32x4 oacc[4] = {};
    for (int js = js0; js < js1; ++js) {
        const bool diag = (js == i);
        #pragma unroll
        for (int sf = 0; sf < 4; ++sf) {
            const long kb = ((long)(b * 128 + js * 4 + sf) * 2) * 512 + lane * 8;
            const bf16x8 kh0 = *(const bf16x8*)&FKH[kb];
            const bf16x8 kh1 = *(const bf16x8*)&FKH[kb + 512];
            const bf16x8 kl0 = *(const bf16x8*)&FKL[kb];
            const bf16x8 kl1 = *(const bf16x8*)&FKL[kb + 512];
            f32x4 cc = {};
            cc = MFMA(kh0, qh0, cc);
            cc = MFMA(kh0, ql0, cc);
            cc = MFMA(kl0, qh0, cc);
            cc = MFMA(kh1, qh1, cc);
            cc = MFMA(kh1, ql1, cc);
            cc = MFMA(kl1, qh1, cc);

            u16 hq[4];
            #pragma unroll
            for (int r = 0; r < 4; ++r) {
                float ev = __expf(cc[r]);
                if (diag && (t_sub < sf * 16 + quad * 4 + r)) ev = 0.f;
                hq[r] = f2bf(ev);
            }
            const int s_sub = sf * 16 + quad * 4;
            const int ch = (s_sub >> 3) ^ (t_sub & 7);
            const int aoff = t_sub * 64 + ch * 8 + (s_sub & 7);
            uint2 pk;
            pk.x = (unsigned)hq[0] | ((unsigned)hq[1] << 16);
            pk.y = (unsigned)hq[2] | ((unsigned)hq[3] << 16);
            *(uint2*)&p_l[aoff] = pk;
        }
        __syncthreads();

        bf16x8 pa[2];
        #pragma unroll
        for (int kcp = 0; kcp < 2; ++kcp) {
            const int row = w * 16 + (lane & 15);
            const int sc = kcp * 32 + (lane >> 4) * 8;
            const int ch = (sc >> 3) ^ (row & 7);
            pa[kcp] = *(const bf16x8*)&p_l[row * 64 + ch * 8];
        }
        #pragma unroll
        for (int nf = 0; nf < 4; ++nf) {
            const long vb = ((long)(b * 4 + nf) * 64 + 2 * js) * 512 + lane * 8;
            const bf16x8 v0 = *(const bf16x8*)&VF[vb];
            const bf16x8 v1 = *(const bf16x8*)&VF[vb + 512];
            oacc[nf] = MFMA(pa[0], v0, oacc[nf]);
            oacc[nf] = MFMA(pa[1], v1, oacc[nf]);
        }
        __syncthreads();   // p_l reused next js
    }

    const bool single = (i < 8);   // one chunk covers the whole row
    #pragma unroll
    for (int nf = 0; nf < 4; ++nf) {
        const int h = nf * 16 + lr;
        #pragma unroll
        for (int r = 0; r < 4; ++r) {
            const int t = t0 + w * 16 + quad * 4 + r;
            const long o = (long)(b * 2048 + t) * 64 + h;
            if (single) out[o] = oacc[nf][r];
            else        atomicAdd(&out[o], oacc[nf][r]);
        }
    }
}

extern "C" void kernel_launch(void* const* d_in, const int* in_sizes, int n_in,
                              void* d_out, int out_size, void* d_ws, size_t ws_size,
                              hipStream_t stream)
{
    const float* idx = (const float*)d_in[0];
    const float* Wk  = (const float*)d_in[1];
    const float* Wq  = (const float*)d_in[2];
    const float* Wv  = (const float*)d_in[3];
    char* ws = (char*)d_ws;
    float* out = (float*)d_out;

    u16* FWH = (u16*)(ws + WH_OFF);
    u16* FQH = (u16*)(ws + FQH_OFF); u16* FQL = (u16*)(ws + FQL_OFF);
    u16* FKH = (u16*)(ws + FKH_OFF); u16* FKL = (u16*)(ws + FKL_OFF);
    u16* VF  = (u16*)(ws + VF_OFF);
    float* Dp = (float*)(ws + DD_OFF);

    hipMemsetAsync(out, 0, (size_t)8 * 2048 * 64 * sizeof(float), stream);
    hipMemsetAsync(Dp, 0, (size_t)8 * 2048 * sizeof(float), stream);

    wsplit_kernel<<<192, 128, 0, stream>>>(Wk, Wq, Wv, FWH);
    qkv_kernel<<<256, 512, 0, stream>>>(idx, FWH, FQH, FQL, FKH, FKL, VF);
    stats_kernel<<<dim3(144, 8), 256, 0, stream>>>(FQH, FQL, FKH, FKL, Dp);
    vscale_kernel<<<512, 256, 0, stream>>>(VF, Dp);
    out_kernel<<<dim3(80, 8), 256, 0, stream>>>(FQH, FQL, FKH, FKL, VF, out);
}

// Round 10
// 150.437 us; speedup vs baseline: 1.0167x; 1.0167x over previous
//
#include <hip/hip_runtime.h>

// B=8, T=2048, C=1024, H=64.  Reference: softmax over QUERY axis (dim=1),
// no 1/sqrt(d) scale.  out[t,h] = sum_{s<=t} exp(q_t.k_s)/D_s * v[s,h],
// D_s = sum_{t>=s} exp(q_t.k_s).
//
// qkv GEMM: 2-term split (exact-A x bf16-W), counted-vmcnt DMA pipeline (r20).
// Q/K stored hi+lo for stats' 3-term QK dots; V, P plain bf16.
// Round-21 (149.8us): swapped QK MFMA (row=s,col=t); P via LDS transpose.
// Round-22 (FAILED 153.0): P elimination — QK recompute in out costs more
// than the P round-trip (67 MB P lives in 256 MB L3, not HBM).  Reverted.
// Round-23: r21 minus the stats LDS transpose.  P stored in QUARTET layout
// PF[b][tblk=t/16][sq=s/4][t&15] (uint2): stats stores its C-layout quartets
// DIRECTLY (coalesced 128B segments, no LDS/barriers in jt loop); out reads
// an A-frag as 2 adjacent quartets (4x8B loads/js).  Bit-identical values.

typedef __attribute__((ext_vector_type(8))) short bf16x8;
typedef __attribute__((ext_vector_type(4))) float f32x4;
typedef unsigned short u16;

#define MFMA(a, b, c) __builtin_amdgcn_mfma_f32_16x16x32_bf16((a), (b), (c), 0, 0, 0)

__device__ __forceinline__ u16 f2bf(float x) {           // RNE fp32 -> bf16
    unsigned u = __float_as_uint(x);
    u += 0x7fff + ((u >> 16) & 1);
    return (u16)(u >> 16);
}
__device__ __forceinline__ float bf2f(u16 h) {
    return __uint_as_float(((unsigned)h) << 16);
}

// trunc-split 8 fp32 -> hi bf16x8 + lo bf16x8 (exact residual).  ~3 VALU/flt.
__device__ __forceinline__ void split8(const f32x4 x0, const f32x4 x1,
                                       bf16x8* hv, bf16x8* lv)
{
    const float f[8] = {x0[0], x0[1], x0[2], x0[3], x1[0], x1[1], x1[2], x1[3]};
    union { unsigned u[4]; bf16x8 v; } H, L;
    #pragma unroll
    for (int j = 0; j < 4; ++j) {
        const unsigned u0 = __float_as_uint(f[2 * j]);
        const unsigned u1 = __float_as_uint(f[2 * j + 1]);
        H.u[j] = __builtin_amdgcn_perm(u1, u0, 0x07060302);   // top16 of each
        const float l0 = f[2 * j]     - __uint_as_float(u0 & 0xffff0000u);
        const float l1 = f[2 * j + 1] - __uint_as_float(u1 & 0xffff0000u);
        L.u[j] = __builtin_amdgcn_perm(__float_as_uint(l1), __float_as_uint(l0),
                                       0x07060302);
    }
    *hv = H.v;
    *lv = L.v;
}

typedef const __attribute__((address_space(1))) void* gas_p;
typedef __attribute__((address_space(3))) void* las_p;

// ws byte offsets
#define WH_OFF  0u
#define WL_OFF  (WH_OFF + 192u*1024u*2u)
#define FQH_OFF (WL_OFF + 192u*1024u*2u)
#define FQL_OFF (FQH_OFF + 2u*1024u*1024u)
#define FKH_OFF (FQL_OFF + 2u*1024u*1024u)
#define FKL_OFF (FKH_OFF + 2u*1024u*1024u)
#define VF_OFF  (FKL_OFF + 2u*1024u*1024u)
#define DD_OFF  (VF_OFF + 2u*1024u*1024u)          // fp32 [B][T] = 64 KB
#define PF_OFF  (DD_OFF + 8u*2048u*4u)             // bf16 quartets, 67 MB

// ---------------------------------------------------------------------------
// W -> fragment-coalesced bf16 (RNE).  Chunk kc (32 K-elems) of col-block
// nblk lives at nblk*16384 + kc*512 u16.
// ---------------------------------------------------------------------------
__global__ __launch_bounds__(128) void wsplit_kernel(
    const float* __restrict__ Wk, const float* __restrict__ Wq,
    const float* __restrict__ Wv, u16* __restrict__ FWH)
{
    const int n = blockIdx.x;                 // 0..191
    const int nblk = n >> 4, lr = n & 15;
    const float* src = (n < 64) ? (Wq + (long)n * 1024)
                     : (n < 128) ? (Wk + (long)(n - 64) * 1024)
                                 : (Wv + (long)(n - 128) * 1024);
    const int f = threadIdx.x;                // 0..127 fragment id
    const int kc = f >> 2, q = f & 3;
    const float4 f0 = *(const float4*)&src[kc * 32 + q * 8];
    const float4 f1 = *(const float4*)&src[kc * 32 + q * 8 + 4];
    const float vs[8] = {f0.x, f0.y, f0.z, f0.w, f1.x, f1.y, f1.z, f1.w};
    bf16x8 hv;
    #pragma unroll
    for (int j = 0; j < 8; ++j) hv[j] = (short)f2bf(vs[j]);
    const long o = ((long)(nblk * 32 + kc) * 64 + q * 16 + lr) * 8;
    *(bf16x8*)&FWH[o] = hv;
}

// ---------------------------------------------------------------------------
// qkv (r20 verbatim).  Counted-vmcnt DMA pipeline, 2-term split, phase K=64,
// 3 stages x 40 KB LDS, 5 DMA/wave/phase, boundary vmcnt(5) + bare s_barrier.
// ---------------------------------------------------------------------------
__global__ __launch_bounds__(512, 2) void qkv_kernel(
    const float* __restrict__ idx, const u16* __restrict__ FWH,
    u16* __restrict__ FQH, u16* __restrict__ FQL,
    u16* __restrict__ FKH, u16* __restrict__ FKL, u16* __restrict__ VF)
{
    __shared__ __align__(16) char smem[3][40960];   // A 16KB + FWH 24KB
    const int tid = threadIdx.x;
    const int w = tid >> 6, lr = tid & 15, quad = (tid >> 4) & 3;
    const int lane = tid & 63;
    const int r0 = blockIdx.x * 64;
    const int b = r0 >> 11, t0 = r0 & 2047;
    const int m0 = (w & 1) * 32;
    const int nbb = (w >> 1) * 3;

    const float* asrc[2];
    int adst[2];
    #pragma unroll
    for (int j = 0; j < 2; ++j) {
        const int s = w * 2 + j;
        const int row = s * 4 + (lane >> 4);
        const int lc = (lane & 15) ^ (row & 7);
        asrc[j] = idx + (long)(r0 + row) * 1024 + lc * 4;
        adst[j] = s * 1024;
    }
    const u16* fsrc[3];
    int fdst[3];
    #pragma unroll
    for (int j = 0; j < 3; ++j) {
        const int seg = w * 3 + j;
        const int nblk = seg >> 1, kcl = seg & 1;
        fsrc[j] = FWH + (long)nblk * 16384 + kcl * 512 + lane * 8;
        fdst[j] = 16384 + seg * 1024;
    }

#define ISSUE(PH)                                                             \
    {                                                                         \
        const int nb_ = (PH) % 3;                                             \
        _Pragma("unroll")                                                     \
        for (int j = 0; j < 2; ++j)                                           \
            __builtin_amdgcn_global_load_lds((gas_p)(asrc[j] + (PH) * 64),    \
                (las_p)(smem[nb_] + adst[j]), 16, 0, 0);                      \
        _Pragma("unroll")                                                     \
        for (int j = 0; j < 3; ++j)                                           \
            __builtin_amdgcn_global_load_lds((gas_p)(fsrc[j] + (long)(PH) * 1024), \
                (las_p)(smem[nb_] + fdst[j]), 16, 0, 0);                      \
    }

#define COMPUTE(PH)                                                           \
    {                                                                         \
        const int nb_ = (PH) % 3;                                             \
        const float* A_ = (const float*)smem[nb_];                            \
        const u16* F_ = (const u16*)(smem[nb_] + 16384);                      \
        _Pragma("unroll")                                                     \
        for (int kc = 0; kc < 2; ++kc) {                                      \
            bf16x8 AH[2], AL[2];                                              \
            _Pragma("unroll")                                                 \
            for (int mi = 0; mi < 2; ++mi) {                                  \
                const int R = m0 + mi * 16 + lr;                              \
                const int c0 = (kc * 8 + quad * 2) ^ (lr & 7);                \
                const f32x4 x0 = *(const f32x4*)&A_[R * 64 + c0 * 4];         \
                const f32x4 x1 = *(const f32x4*)&A_[R * 64 + (c0 ^ 1) * 4];   \
                split8(x0, x1, &AH[mi], &AL[mi]);                             \
            }                                                                 \
            _Pragma("unroll")                                                 \
            for (int nf = 0; nf < 3; ++nf) {                                  \
                const int sb = (((nbb + nf) * 2 + kc)) * 512 + lane * 8;      \
                const bf16x8 bh = *(const bf16x8*)&F_[sb];                    \
                _Pragma("unroll")                                             \
                for (int mi = 0; mi < 2; ++mi) {                              \
                    f32x4 c = acc[mi][nf];                                    \
                    c = MFMA(AH[mi], bh, c);                                  \
                    c = MFMA(AL[mi], bh, c);                                  \
                    acc[mi][nf] = c;                                          \
                }                                                             \
            }                                                                 \
        }                                                                     \
    }

#define WAITV(N)                                                              \
    asm volatile("s_waitcnt vmcnt(" #N ")" ::: "memory");                     \
    __builtin_amdgcn_sched_barrier(0);                                        \
    __builtin_amdgcn_s_barrier();

    f32x4 acc[2][3] = {};

    ISSUE(0); ISSUE(1);
    WAITV(5)

    for (int ph = 0; ph < 14; ++ph) {
        ISSUE(ph + 2);
        __builtin_amdgcn_sched_barrier(0);
        COMPUTE(ph);
        WAITV(5)
    }
    COMPUTE(14);
    WAITV(0)
    COMPUTE(15);

#undef WAITV
#undef COMPUTE
#undef ISSUE

    #pragma unroll
    for (int mi = 0; mi < 2; ++mi) {
        const int tb = t0 + m0 + mi * 16 + quad * 4;
        const int tblk = (t0 + m0 + mi * 16) >> 4;
        #pragma unroll
        for (int nf = 0; nf < 3; ++nf) {
            const int n = (nbb + nf) * 16 + lr;
            const f32x4 a = acc[mi][nf];
            if (n < 128) {
                u16* Hd = (n < 64) ? FQH : FKH;
                u16* Ld = (n < 64) ? FQL : FKL;
                const int h = n & 63;
                const int kc = h >> 5;
                const int lsub = 16 * ((h & 31) >> 3);
                const long base = ((long)(b * 128 + tblk) * 2 + kc) * 512 + (h & 7);
                #pragma unroll
                for (int r = 0; r < 4; ++r) {
                    const float v = a[r];
                    const u16 hi = f2bf(v);
                    const u16 lo = f2bf(v - bf2f(hi));
                    const long o = base + (long)(quad * 4 + r + lsub) * 8;
                    Hd[o] = hi; Ld[o] = lo;
                }
            } else {
                const int h = n - 128;
                const int hblk = h >> 4;
                #pragma unroll
                for (int r = 0; r < 4; ++r) {
                    const int t = tb + r;
                    const long o = ((long)(b * 4 + hblk) * 64 + (t >> 5)) * 512
                                 + (long)(16 * ((t & 31) >> 3) + (h & 15)) * 8 + (t & 7);
                    VF[o] = f2bf(a[r]);
                }
            }
        }
    }
}

// ---------------------------------------------------------------------------
// stats: D_s = sum_{t>=s} exp(q_t.k_s) AND stores P = exp (masked, bf16) in
// QUARTET layout.  Swapped MFMA: cc = mfma(K, Q) -> thread holds
// s = s0+sf*16+quad*4+r (consecutive in r), t = jt*64+w*16+lr.
// Quartet -> one uint2 global store at [b][tblk=jt*4+w][sq=i*16+sf*4+quad][lr]
// (16 lanes x 8B = 128B contiguous per (w,sf,quad)).  No LDS in jt loop.
// D: shfl_xor over lr bits; red[4][64] + atomicAdd.
// Grid (144, B): s-tile i, t-chunk x (<=4 t-tiles).
// ---------------------------------------------------------------------------
__global__ __launch_bounds__(256, 4) void stats_kernel(
    const u16* __restrict__ FQH, const u16* __restrict__ FQL,
    const u16* __restrict__ FKH, const u16* __restrict__ FKL,
    u16* __restrict__ PF, float* __restrict__ D)
{
    __shared__ float red[4][64];
    const int tid = threadIdx.x;
    const int w = tid >> 6, lr = tid & 15, quad = (tid >> 4) & 3;
    const int lane = tid & 63;
    const int b = blockIdx.y;
    int x = blockIdx.x, i = 0;
    for (;;) { const int nc = (35 - i) >> 2; if (x < nc) break; x -= nc; ++i; }
    const int s0 = i * 64;
    const int jt0 = i + 4 * x, jt1 = min(jt0 + 4, 32);

    uint2* __restrict__ PQ = (uint2*)PF;

    // K frags hoisted (A-operand rows = s); sf = s-subtile 0..3.
    bf16x8 KH[4][2], KL[4][2];
    #pragma unroll
    for (int sf = 0; sf < 4; ++sf) {
        const long kb = ((long)(b * 128 + i * 4 + sf) * 2) * 512 + lane * 8;
        KH[sf][0] = *(const bf16x8*)&FKH[kb];
        KH[sf][1] = *(const bf16x8*)&FKH[kb + 512];
        KL[sf][0] = *(const bf16x8*)&FKL[kb];
        KL[sf][1] = *(const bf16x8*)&FKL[kb + 512];
    }

    float dsum[4][4] = {};
    for (int jt = jt0; jt < jt1; ++jt) {
        const long qb = ((long)(b * 128 + jt * 4 + w) * 2) * 512 + lane * 8;
        const bf16x8 qh0 = *(const bf16x8*)&FQH[qb];
        const bf16x8 qh1 = *(const bf16x8*)&FQH[qb + 512];
        const bf16x8 ql0 = *(const bf16x8*)&FQL[qb];
        const bf16x8 ql1 = *(const bf16x8*)&FQL[qb + 512];
        const bool diag = (jt == i);
        const int t_sub = w * 16 + lr;
        const long tb_base = ((long)(b * 128 + jt * 4 + w)) * 512;
        #pragma unroll
        for (int sf = 0; sf < 4; ++sf) {
            f32x4 cc = {};
            cc = MFMA(KH[sf][0], qh0, cc);
            cc = MFMA(KH[sf][0], ql0, cc);
            cc = MFMA(KL[sf][0], qh0, cc);
            cc = MFMA(KH[sf][1], qh1, cc);
            cc = MFMA(KH[sf][1], ql1, cc);
            cc = MFMA(KL[sf][1], qh1, cc);

            u16 hq[4];
            #pragma unroll
            for (int r = 0; r < 4; ++r) {
                float ev = __expf(cc[r]);
                if (diag && (t_sub < sf * 16 + quad * 4 + r)) ev = 0.f;
                dsum[sf][r] += ev;
                hq[r] = f2bf(ev);
            }
            uint2 pk;
            pk.x = (unsigned)hq[0] | ((unsigned)hq[1] << 16);
            pk.y = (unsigned)hq[2] | ((unsigned)hq[3] << 16);
            PQ[(tb_base + i * 16 + sf * 4 + quad) * 16 + lr] = pk;
        }
    }

    #pragma unroll
    for (int sf = 0; sf < 4; ++sf)
        #pragma unroll
        for (int r = 0; r < 4; ++r) {
            float v = dsum[sf][r];
            v += __shfl_xor(v, 1);
            v += __shfl_xor(v, 2);
            v += __shfl_xor(v, 4);
            v += __shfl_xor(v, 8);
            dsum[sf][r] = v;
        }
    if (lr == 0) {
        #pragma unroll
        for (int sf = 0; sf < 4; ++sf)
            #pragma unroll
            for (int r = 0; r < 4; ++r)
                red[w][sf * 16 + quad * 4 + r] = dsum[sf][r];
    }
    __syncthreads();
    if (tid < 64)
        atomicAdd(&D[b * 2048 + s0 + tid],
                  red[0][tid] + red[1][tid] + red[2][tid] + red[3][tid]);
}

// ---------------------------------------------------------------------------
// vscale: VF (B-fragment layout) *= 1/D[s].
// ---------------------------------------------------------------------------
__global__ __launch_bounds__(256) void vscale_kernel(
    u16* __restrict__ VF, const float* __restrict__ D)
{
    const int g = blockIdx.x * 256 + threadIdx.x;   // 131072 threads x 8 u16
    const long e = (long)g * 8;
    const int lane = (int)((e >> 3) & 63);
    const int kc   = (int)((e >> 9) & 63);
    const int b    = (int)(e >> 17);
    const int s = kc * 32 + (lane >> 4) * 8;
    const float4 d0 = *(const float4*)&D[b * 2048 + s];
    const float4 d1 = *(const float4*)&D[b * 2048 + s + 4];
    const float dv[8] = {d0.x, d0.y, d0.z, d0.w, d1.x, d1.y, d1.z, d1.w};
    bf16x8 vv = *(bf16x8*)&VF[e];
    bf16x8 ov;
    #pragma unroll
    for (int j = 0; j < 8; ++j)
        ov[j] = (short)f2bf(bf2f((u16)vv[j]) / dv[j]);
    *(bf16x8*)&VF[e] = ov;
}

// ---------------------------------------------------------------------------
// out: pure streaming PV GEMM.  out[t][h] = sum_{s<=t} P[t][s] * Vtilde[s][h].
// P A-frag assembled from 2 adjacent quartets: lane l needs t=l&15,
// s = js*64 + kcp*32 + (l>>4)*8 + 0..7 -> uint2 at
// [(b*128+tblk)*512 + js*16+kcp*8+(l>>4)*2 (+1)][l&15].  4x8B loads per js.
// Grid (80, B): t-tile i, s-chunk x (<=8 s-tiles); atomicAdd for i>=8.
// ---------------------------------------------------------------------------
__global__ __launch_bounds__(256, 4) void out_kernel(
    const u16* __restrict__ PF, const u16* __restrict__ VF,
    float* __restrict__ out)
{
    const int tid = threadIdx.x;
    const int w = tid >> 6, lr = tid & 15, quad = (tid >> 4) & 3;
    const int lane = tid & 63;
    const int b = blockIdx.y;
    int x = blockIdx.x, i = 0;
    for (;;) { const int nc = (i + 8) >> 3; if (x < nc) break; x -= nc; ++i; }
    const int t0 = i * 64;
    const int js0 = 8 * x, js1 = min(8 * x + 8, i + 1);
    const int tblk = i * 4 + w;

    const uint2* __restrict__ PQ = (const uint2*)PF;
    const int g = lane >> 4, tr = lane & 15;
    const long tb_base = ((long)(b * 128 + tblk)) * 512;

    f32x4 oacc[4] = {};
    for (int js = js0; js < js1; ++js) {
        bf16x8 pa[2];
        #pragma unroll
        for (int kcp = 0; kcp < 2; ++kcp) {
            const long u = (tb_base + js * 16 + kcp * 8 + g * 2) * 16 + tr;
            const uint2 a0 = PQ[u];
            const uint2 a1 = PQ[u + 16];
            union { unsigned uu[4]; bf16x8 v; } P_;
            P_.uu[0] = a0.x; P_.uu[1] = a0.y; P_.uu[2] = a1.x; P_.uu[3] = a1.y;
            pa[kcp] = P_.v;
        }
        #pragma unroll
        for (int nf = 0; nf < 4; ++nf) {
            const long vb = ((long)(b * 4 + nf) * 64 + 2 * js) * 512 + lane * 8;
            const bf16x8 v0 = *(const bf16x8*)&VF[vb];
            const bf16x8 v1 = *(const bf16x8*)&VF[vb + 512];
            oacc[nf] = MFMA(pa[0], v0, oacc[nf]);
            oacc[nf] = MFMA(pa[1], v1, oacc[nf]);
        }
    }

    const bool single = (i < 8);   // one chunk covers the whole row
    #pragma unroll
    for (int nf = 0; nf < 4; ++nf) {
        const int h = nf * 16 + lr;
        #pragma unroll
        for (int r = 0; r < 4; ++r) {
            const int t = t0 + w * 16 + quad * 4 + r;
            const long o = (long)(b * 2048 + t) * 64 + h;
            if (single) out[o] = oacc[nf][r];
            else        atomicAdd(&out[o], oacc[nf][r]);
        }
    }
}

extern "C" void kernel_launch(void* const* d_in, const int* in_sizes, int n_in,
                              void* d_out, int out_size, void* d_ws, size_t ws_size,
                              hipStream_t stream)
{
    const float* idx = (const float*)d_in[0];
    const float* Wk  = (const float*)d_in[1];
    const float* Wq  = (const float*)d_in[2];
    const float* Wv  = (const float*)d_in[3];
    char* ws = (char*)d_ws;
    float* out = (float*)d_out;

    u16* FWH = (u16*)(ws + WH_OFF);
    u16* FQH = (u16*)(ws + FQH_OFF); u16* FQL = (u16*)(ws + FQL_OFF);
    u16* FKH = (u16*)(ws + FKH_OFF); u16* FKL = (u16*)(ws + FKL_OFF);
    u16* VF  = (u16*)(ws + VF_OFF);
    float* Dp = (float*)(ws + DD_OFF);
    u16* PF  = (u16*)(ws + PF_OFF);

    hipMemsetAsync(out, 0, (size_t)8 * 2048 * 64 * sizeof(float), stream);
    hipMemsetAsync(Dp, 0, (size_t)8 * 2048 * sizeof(float), stream);

    wsplit_kernel<<<192, 128, 0, stream>>>(Wk, Wq, Wv, FWH);
    qkv_kernel<<<256, 512, 0, stream>>>(idx, FWH, FQH, FQL, FKH, FKL, VF);
    stats_kernel<<<dim3(144, 8), 256, 0, stream>>>(FQH, FQL, FKH, FKL, PF, Dp);
    vscale_kernel<<<512, 256, 0, stream>>>(VF, Dp);
    out_kernel<<<dim3(80, 8), 256, 0, stream>>>(PF, VF, out);
}

// Round 11
// 145.871 us; speedup vs baseline: 1.0486x; 1.0313x over previous
//
#include <hip/hip_runtime.h>

// B=8, T=2048, C=1024, H=64.  Reference: softmax over QUERY axis (dim=1),
// no 1/sqrt(d) scale.  out[t,h] = sum_{s<=t} exp(q_t.k_s)/D_s * v[s,h],
// D_s = sum_{t>=s} exp(q_t.k_s).
//
// qkv GEMM: 2-term split (exact-A x bf16-W), counted-vmcnt DMA pipeline (r20).
// Round-21 (149.8): swapped QK MFMA (row=s,col=t).  Round-22 (FAILED): P
// elimination.  Round-23 (neutral): quartet P layout (no LDS transpose).
// Round-24: cut stats arithmetic.  (1) QK dots 3-term -> 2-term: S =
// (qh+ql)*kh, K plain RNE bf16 (sigma(dS) ~ 3.6e-3 -> ~0.4% P error, same
// class as bf16 P/V rounding).  FKL never written/read.  (2) stats jt-chunk
// 4 -> 8 (grid 80 per b): K-hoist amortized 2x, 640 blocks = single round,
// less D atomic contention.

typedef __attribute__((ext_vector_type(8))) short bf16x8;
typedef __attribute__((ext_vector_type(4))) float f32x4;
typedef unsigned short u16;

#define MFMA(a, b, c) __builtin_amdgcn_mfma_f32_16x16x32_bf16((a), (b), (c), 0, 0, 0)

__device__ __forceinline__ u16 f2bf(float x) {           // RNE fp32 -> bf16
    unsigned u = __float_as_uint(x);
    u += 0x7fff + ((u >> 16) & 1);
    return (u16)(u >> 16);
}
__device__ __forceinline__ float bf2f(u16 h) {
    return __uint_as_float(((unsigned)h) << 16);
}

// trunc-split 8 fp32 -> hi bf16x8 + lo bf16x8 (exact residual).  ~3 VALU/flt.
__device__ __forceinline__ void split8(const f32x4 x0, const f32x4 x1,
                                       bf16x8* hv, bf16x8* lv)
{
    const float f[8] = {x0[0], x0[1], x0[2], x0[3], x1[0], x1[1], x1[2], x1[3]};
    union { unsigned u[4]; bf16x8 v; } H, L;
    #pragma unroll
    for (int j = 0; j < 4; ++j) {
        const unsigned u0 = __float_as_uint(f[2 * j]);
        const unsigned u1 = __float_as_uint(f[2 * j + 1]);
        H.u[j] = __builtin_amdgcn_perm(u1, u0, 0x07060302);   // top16 of each
        const float l0 = f[2 * j]     - __uint_as_float(u0 & 0xffff0000u);
        const float l1 = f[2 * j + 1] - __uint_as_float(u1 & 0xffff0000u);
        L.u[j] = __builtin_amdgcn_perm(__float_as_uint(l1), __float_as_uint(l0),
                                       0x07060302);
    }
    *hv = H.v;
    *lv = L.v;
}

typedef const __attribute__((address_space(1))) void* gas_p;
typedef __attribute__((address_space(3))) void* las_p;

// ws byte offsets
#define WH_OFF  0u
#define WL_OFF  (WH_OFF + 192u*1024u*2u)
#define FQH_OFF (WL_OFF + 192u*1024u*2u)
#define FQL_OFF (FQH_OFF + 2u*1024u*1024u)
#define FKH_OFF (FQL_OFF + 2u*1024u*1024u)
#define FKL_OFF (FKH_OFF + 2u*1024u*1024u)
#define VF_OFF  (FKL_OFF + 2u*1024u*1024u)
#define DD_OFF  (VF_OFF + 2u*1024u*1024u)          // fp32 [B][T] = 64 KB
#define PF_OFF  (DD_OFF + 8u*2048u*4u)             // bf16 quartets, 67 MB

// ---------------------------------------------------------------------------
// W -> fragment-coalesced bf16 (RNE).  Chunk kc (32 K-elems) of col-block
// nblk lives at nblk*16384 + kc*512 u16.
// ---------------------------------------------------------------------------
__global__ __launch_bounds__(128) void wsplit_kernel(
    const float* __restrict__ Wk, const float* __restrict__ Wq,
    const float* __restrict__ Wv, u16* __restrict__ FWH)
{
    const int n = blockIdx.x;                 // 0..191
    const int nblk = n >> 4, lr = n & 15;
    const float* src = (n < 64) ? (Wq + (long)n * 1024)
                     : (n < 128) ? (Wk + (long)(n - 64) * 1024)
                                 : (Wv + (long)(n - 128) * 1024);
    const int f = threadIdx.x;                // 0..127 fragment id
    const int kc = f >> 2, q = f & 3;
    const float4 f0 = *(const float4*)&src[kc * 32 + q * 8];
    const float4 f1 = *(const float4*)&src[kc * 32 + q * 8 + 4];
    const float vs[8] = {f0.x, f0.y, f0.z, f0.w, f1.x, f1.y, f1.z, f1.w};
    bf16x8 hv;
    #pragma unroll
    for (int j = 0; j < 8; ++j) hv[j] = (short)f2bf(vs[j]);
    const long o = ((long)(nblk * 32 + kc) * 64 + q * 16 + lr) * 8;
    *(bf16x8*)&FWH[o] = hv;
}

// ---------------------------------------------------------------------------
// qkv (r20 structure).  Counted-vmcnt DMA pipeline, 2-term split, phase K=64,
// 3 stages x 40 KB LDS, 5 DMA/wave/phase, boundary vmcnt(5) + bare s_barrier.
// Epilogue: FQ hi+lo, FK hi only (K-lo unused after r24), V bf16.
// ---------------------------------------------------------------------------
__global__ __launch_bounds__(512, 2) void qkv_kernel(
    const float* __restrict__ idx, const u16* __restrict__ FWH,
    u16* __restrict__ FQH, u16* __restrict__ FQL,
    u16* __restrict__ FKH, u16* __restrict__ VF)
{
    __shared__ __align__(16) char smem[3][40960];   // A 16KB + FWH 24KB
    const int tid = threadIdx.x;
    const int w = tid >> 6, lr = tid & 15, quad = (tid >> 4) & 3;
    const int lane = tid & 63;
    const int r0 = blockIdx.x * 64;
    const int b = r0 >> 11, t0 = r0 & 2047;
    const int m0 = (w & 1) * 32;
    const int nbb = (w >> 1) * 3;

    const float* asrc[2];
    int adst[2];
    #pragma unroll
    for (int j = 0; j < 2; ++j) {
        const int s = w * 2 + j;
        const int row = s * 4 + (lane >> 4);
        const int lc = (lane & 15) ^ (row & 7);
        asrc[j] = idx + (long)(r0 + row) * 1024 + lc * 4;
        adst[j] = s * 1024;
    }
    const u16* fsrc[3];
    int fdst[3];
    #pragma unroll
    for (int j = 0; j < 3; ++j) {
        const int seg = w * 3 + j;
        const int nblk = seg >> 1, kcl = seg & 1;
        fsrc[j] = FWH + (long)nblk * 16384 + kcl * 512 + lane * 8;
        fdst[j] = 16384 + seg * 1024;
    }

#define ISSUE(PH)                                                             \
    {                                                                         \
        const int nb_ = (PH) % 3;                                             \
        _Pragma("unroll")                                                     \
        for (int j = 0; j < 2; ++j)                                           \
            __builtin_amdgcn_global_load_lds((gas_p)(asrc[j] + (PH) * 64),    \
                (las_p)(smem[nb_] + adst[j]), 16, 0, 0);                      \
        _Pragma("unroll")                                                     \
        for (int j = 0; j < 3; ++j)                                           \
            __builtin_amdgcn_global_load_lds((gas_p)(fsrc[j] + (long)(PH) * 1024), \
                (las_p)(smem[nb_] + fdst[j]), 16, 0, 0);                      \
    }

#define COMPUTE(PH)                                                           \
    {                                                                         \
        const int nb_ = (PH) % 3;                                             \
        const float* A_ = (const float*)smem[nb_];                            \
        const u16* F_ = (const u16*)(smem[nb_] + 16384);                      \
        _Pragma("unroll")                                                     \
        for (int kc = 0; kc < 2; ++kc) {                                      \
            bf16x8 AH[2], AL[2];                                              \
            _Pragma("unroll")                                                 \
            for (int mi = 0; mi < 2; ++mi) {                                  \
                const int R = m0 + mi * 16 + lr;                              \
                const int c0 = (kc * 8 + quad * 2) ^ (lr & 7);                \
                const f32x4 x0 = *(const f32x4*)&A_[R * 64 + c0 * 4];         \
                const f32x4 x1 = *(const f32x4*)&A_[R * 64 + (c0 ^ 1) * 4];   \
                split8(x0, x1, &AH[mi], &AL[mi]);                             \
            }                                                                 \
            _Pragma("unroll")                                                 \
            for (int nf = 0; nf < 3; ++nf) {                                  \
                const int sb = (((nbb + nf) * 2 + kc)) * 512 + lane * 8;      \
                const bf16x8 bh = *(const bf16x8*)&F_[sb];                    \
                _Pragma("unroll")                                             \
                for (int mi = 0; mi < 2; ++mi) {                              \
                    f32x4 c = acc[mi][nf];                                    \
                    c = MFMA(AH[mi], bh, c);                                  \
                    c = MFMA(AL[mi], bh, c);                                  \
                    acc[mi][nf] = c;                                          \
                }                                                             \
            }                                                                 \
        }                                                                     \
    }

#define WAITV(N)                                                              \
    asm volatile("s_waitcnt vmcnt(" #N ")" ::: "memory");                     \
    __builtin_amdgcn_sched_barrier(0);                                        \
    __builtin_amdgcn_s_barrier();

    f32x4 acc[2][3] = {};

    ISSUE(0); ISSUE(1);
    WAITV(5)

    for (int ph = 0; ph < 14; ++ph) {
        ISSUE(ph + 2);
        __builtin_amdgcn_sched_barrier(0);
        COMPUTE(ph);
        WAITV(5)
    }
    COMPUTE(14);
    WAITV(0)
    COMPUTE(15);

#undef WAITV
#undef COMPUTE
#undef ISSUE

    #pragma unroll
    for (int mi = 0; mi < 2; ++mi) {
        const int tb = t0 + m0 + mi * 16 + quad * 4;
        const int tblk = (t0 + m0 + mi * 16) >> 4;
        #pragma unroll
        for (int nf = 0; nf < 3; ++nf) {
            const int n = (nbb + nf) * 16 + lr;
            const f32x4 a = acc[mi][nf];
            if (n < 128) {
                const bool isQ = (n < 64);
                const int h = n & 63;
                const int kc = h >> 5;
                const int lsub = 16 * ((h & 31) >> 3);
                const long base = ((long)(b * 128 + tblk) * 2 + kc) * 512 + (h & 7);
                #pragma unroll
                for (int r = 0; r < 4; ++r) {
                    const float v = a[r];
                    const u16 hi = f2bf(v);
                    const long o = base + (long)(quad * 4 + r + lsub) * 8;
                    if (isQ) {
                        FQH[o] = hi;
                        FQL[o] = f2bf(v - bf2f(hi));
                    } else {
                        FKH[o] = hi;       // K-lo dropped (2-term QK, r24)
                    }
                }
            } else {
                const int h = n - 128;
                const int hblk = h >> 4;
                #pragma unroll
                for (int r = 0; r < 4; ++r) {
                    const int t = tb + r;
                    const long o = ((long)(b * 4 + hblk) * 64 + (t >> 5)) * 512
                                 + (long)(16 * ((t & 31) >> 3) + (h & 15)) * 8 + (t & 7);
                    VF[o] = f2bf(a[r]);
                }
            }
        }
    }
}

// ---------------------------------------------------------------------------
// stats: D_s = sum_{t>=s} exp(q_t.k_s) AND stores P (masked, bf16) in
// QUARTET layout.  2-term QK: S = kh·(qh+ql), 4 MFMA per (sf,jt).
// Swapped MFMA: thread holds s = s0+sf*16+quad*4+r, t = jt*64+w*16+lr.
// Quartet -> uint2 store at [b][tblk=jt*4+w][sq=i*16+sf*4+quad][lr].
// Grid (80, B): s-tile i, t-chunk x of 8 jt (nc = (39-i)>>3).
// ---------------------------------------------------------------------------
__global__ __launch_bounds__(256, 4) void stats_kernel(
    const u16* __restrict__ FQH, const u16* __restrict__ FQL,
    const u16* __restrict__ FKH,
    u16* __restrict__ PF, float* __restrict__ D)
{
    __shared__ float red[4][64];
    const int tid = threadIdx.x;
    const int w = tid >> 6, lr = tid & 15, quad = (tid >> 4) & 3;
    const int lane = tid & 63;
    const int b = blockIdx.y;
    int x = blockIdx.x, i = 0;
    for (;;) { const int nc = (39 - i) >> 3; if (x < nc) break; x -= nc; ++i; }
    const int s0 = i * 64;
    const int jt0 = i + 8 * x, jt1 = min(jt0 + 8, 32);

    uint2* __restrict__ PQ = (uint2*)PF;

    // K hi frags hoisted (A-operand rows = s); sf = s-subtile 0..3.
    bf16x8 KH[4][2];
    #pragma unroll
    for (int sf = 0; sf < 4; ++sf) {
        const long kb = ((long)(b * 128 + i * 4 + sf) * 2) * 512 + lane * 8;
        KH[sf][0] = *(const bf16x8*)&FKH[kb];
        KH[sf][1] = *(const bf16x8*)&FKH[kb + 512];
    }

    float dsum[4][4] = {};
    for (int jt = jt0; jt < jt1; ++jt) {
        const long qb = ((long)(b * 128 + jt * 4 + w) * 2) * 512 + lane * 8;
        const bf16x8 qh0 = *(const bf16x8*)&FQH[qb];
        const bf16x8 qh1 = *(const bf16x8*)&FQH[qb + 512];
        const bf16x8 ql0 = *(const bf16x8*)&FQL[qb];
        const bf16x8 ql1 = *(const bf16x8*)&FQL[qb + 512];
        const bool diag = (jt == i);
        const int t_sub = w * 16 + lr;
        const long tb_base = ((long)(b * 128 + jt * 4 + w)) * 512;
        #pragma unroll
        for (int sf = 0; sf < 4; ++sf) {
            f32x4 cc = {};
            cc = MFMA(KH[sf][0], qh0, cc);
            cc = MFMA(KH[sf][0], ql0, cc);
            cc = MFMA(KH[sf][1], qh1, cc);
            cc = MFMA(KH[sf][1], ql1, cc);

            u16 hq[4];
            #pragma unroll
            for (int r = 0; r < 4; ++r) {
                float ev = __expf(cc[r]);
                if (diag && (t_sub < sf * 16 + quad * 4 + r)) ev = 0.f;
                dsum[sf][r] += ev;
                hq[r] = f2bf(ev);
            }
            uint2 pk;
            pk.x = (unsigned)hq[0] | ((unsigned)hq[1] << 16);
            pk.y = (unsigned)hq[2] | ((unsigned)hq[3] << 16);
            PQ[(tb_base + i * 16 + sf * 4 + quad) * 16 + lr] = pk;
        }
    }

    #pragma unroll
    for (int sf = 0; sf < 4; ++sf)
        #pragma unroll
        for (int r = 0; r < 4; ++r) {
            float v = dsum[sf][r];
            v += __shfl_xor(v, 1);
            v += __shfl_xor(v, 2);
            v += __shfl_xor(v, 4);
            v += __shfl_xor(v, 8);
            dsum[sf][r] = v;
        }
    if (lr == 0) {
        #pragma unroll
        for (int sf = 0; sf < 4; ++sf)
            #pragma unroll
            for (int r = 0; r < 4; ++r)
                red[w][sf * 16 + quad * 4 + r] = dsum[sf][r];
    }
    __syncthreads();
    if (tid < 64)
        atomicAdd(&D[b * 2048 + s0 + tid],
                  red[0][tid] + red[1][tid] + red[2][tid] + red[3][tid]);
}

// ---------------------------------------------------------------------------
// vscale: VF (B-fragment layout) *= 1/D[s].
// ---------------------------------------------------------------------------
__global__ __launch_bounds__(256) void vscale_kernel(
    u16* __restrict__ VF, const float* __restrict__ D)
{
    const int g = blockIdx.x * 256 + threadIdx.x;   // 131072 threads x 8 u16
    const long e = (long)g * 8;
    const int lane = (int)((e >> 3) & 63);
    const int kc   = (int)((e >> 9) & 63);
    const int b    = (int)(e >> 17);
    const int s = kc * 32 + (lane >> 4) * 8;
    const float4 d0 = *(const float4*)&D[b * 2048 + s];
    const float4 d1 = *(const float4*)&D[b * 2048 + s + 4];
    const float dv[8] = {d0.x, d0.y, d0.z, d0.w, d1.x, d1.y, d1.z, d1.w};
    bf16x8 vv = *(bf16x8*)&VF[e];
    bf16x8 ov;
    #pragma unroll
    for (int j = 0; j < 8; ++j)
        ov[j] = (short)f2bf(bf2f((u16)vv[j]) / dv[j]);
    *(bf16x8*)&VF[e] = ov;
}

// ---------------------------------------------------------------------------
// out: pure streaming PV GEMM.  out[t][h] = sum_{s<=t} P[t][s] * Vtilde[s][h].
// P A-frag assembled from 2 adjacent quartets (4x8B loads/js).
// Grid (80, B): t-tile i, s-chunk x (<=8 s-tiles); atomicAdd for i>=8.
// ---------------------------------------------------------------------------
__global__ __launch_bounds__(256, 4) void out_kernel(
    const u16* __restrict__ PF, const u16* __restrict__ VF,
    float* __restrict__ out)
{
    const int tid = threadIdx.x;
    const int w = tid >> 6, lr = tid & 15, quad = (tid >> 4) & 3;
    const int lane = tid & 63;
    const int b = blockIdx.y;
    int x = blockIdx.x, i = 0;
    for (;;) { const int nc = (i + 8) >> 3; if (x < nc) break; x -= nc; ++i; }
    const int t0 = i * 64;
    const int js0 = 8 * x, js1 = min(8 * x + 8, i + 1);
    const int tblk = i * 4 + w;

    const uint2* __restrict__ PQ = (const uint2*)PF;
    const int g = lane >> 4, tr = lane & 15;
    const long tb_base = ((long)(b * 128 + tblk)) * 512;

    f32x4 oacc[4] = {};
    for (int js = js0; js < js1; ++js) {
        bf16x8 pa[2];
        #pragma unroll
        for (int kcp = 0; kcp < 2; ++kcp) {
            const long u = (tb_base + js * 16 + kcp * 8 + g * 2) * 16 + tr;
            const uint2 a0 = PQ[u];
            const uint2 a1 = PQ[u + 16];
            union { unsigned uu[4]; bf16x8 v; } P_;
            P_.uu[0] = a0.x; P_.uu[1] = a0.y; P_.uu[2] = a1.x; P_.uu[3] = a1.y;
            pa[kcp] = P_.v;
        }
        #pragma unroll
        for (int nf = 0; nf < 4; ++nf) {
            const long vb = ((long)(b * 4 + nf) * 64 + 2 * js) * 512 + lane * 8;
            const bf16x8 v0 = *(const bf16x8*)&VF[vb];
            const bf16x8 v1 = *(const bf16x8*)&VF[vb + 512];
            oacc[nf] = MFMA(pa[0], v0, oacc[nf]);
            oacc[nf] = MFMA(pa[1], v1, oacc[nf]);
        }
    }

    const bool single = (i < 8);   // one chunk covers the whole row
    #pragma unroll
    for (int nf = 0; nf < 4; ++nf) {
        const int h = nf * 16 + lr;
        #pragma unroll
        for (int r = 0; r < 4; ++r) {
            const int t = t0 + w * 16 + quad * 4 + r;
            const long o = (long)(b * 2048 + t) * 64 + h;
            if (single) out[o] = oacc[nf][r];
            else        atomicAdd(&out[o], oacc[nf][r]);
        }
    }
}

extern "C" void kernel_launch(void* const* d_in, const int* in_sizes, int n_in,
                              void* d_out, int out_size, void* d_ws, size_t ws_size,
                              hipStream_t stream)
{
    const float* idx = (const float*)d_in[0];
    const float* Wk  = (const float*)d_in[1];
    const float* Wq  = (const float*)d_in[2];
    const float* Wv  = (const float*)d_in[3];
    char* ws = (char*)d_ws;
    float* out = (float*)d_out;

    u16* FWH = (u16*)(ws + WH_OFF);
    u16* FQH = (u16*)(ws + FQH_OFF); u16* FQL = (u16*)(ws + FQL_OFF);
    u16* FKH = (u16*)(ws + FKH_OFF);
    u16* VF  = (u16*)(ws + VF_OFF);
    float* Dp = (float*)(ws + DD_OFF);
    u16* PF  = (u16*)(ws + PF_OFF);

    hipMemsetAsync(out, 0, (size_t)8 * 2048 * 64 * sizeof(float), stream);
    hipMemsetAsync(Dp, 0, (size_t)8 * 2048 * sizeof(float), stream);

    wsplit_kernel<<<192, 128, 0, stream>>>(Wk, Wq, Wv, FWH);
    qkv_kernel<<<256, 512, 0, stream>>>(idx, FWH, FQH, FQL, FKH, VF);
    stats_kernel<<<dim3(80, 8), 256, 0, stream>>>(FQH, FQL, FKH, PF, Dp);
    vscale_kernel<<<512, 256, 0, stream>>>(VF, Dp);
    out_kernel<<<dim3(80, 8), 256, 0, stream>>>(PF, VF, out);
}

// Round 12
// 142.829 us; speedup vs baseline: 1.0709x; 1.0213x over previous
//
#include <hip/hip_runtime.h>

// B=8, T=2048, C=1024, H=64.  Reference: softmax over QUERY axis (dim=1),
// no 1/sqrt(d) scale.  out[t,h] = sum_{s<=t} exp(q_t.k_s)/D_s * v[s,h],
// D_s = sum_{t>=s} exp(q_t.k_s).
//
// qkv GEMM: 2-term split (exact-A x bf16-W), counted-vmcnt DMA pipeline (r20).
// r21: swapped QK MFMA.  r23: quartet P layout.  r24 (145.9): 2-term QK
// (K-lo dropped) + jt-chunk 8.
// Round-25: (1) Q-lo dropped too -> full-bf16 QK: sigma(dS) ~ 5e-3, still
// under the bf16 P/V rounding floor; stats MFMA 4->2 per (sf,jt), Q reads
// halve, qkv epilogue stores only Q-hi.  (2) vscale folded into out: P
// A-frags scaled by 1/D (same s-vector as the frag; 16 rcp+mul per js) --
// kills a dispatch + 8 MB VF rewrite.  V stays unscaled bf16.

typedef __attribute__((ext_vector_type(8))) short bf16x8;
typedef __attribute__((ext_vector_type(4))) float f32x4;
typedef unsigned short u16;

#define MFMA(a, b, c) __builtin_amdgcn_mfma_f32_16x16x32_bf16((a), (b), (c), 0, 0, 0)

__device__ __forceinline__ u16 f2bf(float x) {           // RNE fp32 -> bf16
    unsigned u = __float_as_uint(x);
    u += 0x7fff + ((u >> 16) & 1);
    return (u16)(u >> 16);
}
__device__ __forceinline__ float bf2f(u16 h) {
    return __uint_as_float(((unsigned)h) << 16);
}

// trunc-split 8 fp32 -> hi bf16x8 + lo bf16x8 (exact residual).  ~3 VALU/flt.
__device__ __forceinline__ void split8(const f32x4 x0, const f32x4 x1,
                                       bf16x8* hv, bf16x8* lv)
{
    const float f[8] = {x0[0], x0[1], x0[2], x0[3], x1[0], x1[1], x1[2], x1[3]};
    union { unsigned u[4]; bf16x8 v; } H, L;
    #pragma unroll
    for (int j = 0; j < 4; ++j) {
        const unsigned u0 = __float_as_uint(f[2 * j]);
        const unsigned u1 = __float_as_uint(f[2 * j + 1]);
        H.u[j] = __builtin_amdgcn_perm(u1, u0, 0x07060302);   // top16 of each
        const float l0 = f[2 * j]     - __uint_as_float(u0 & 0xffff0000u);
        const float l1 = f[2 * j + 1] - __uint_as_float(u1 & 0xffff0000u);
        L.u[j] = __builtin_amdgcn_perm(__float_as_uint(l1), __float_as_uint(l0),
                                       0x07060302);
    }
    *hv = H.v;
    *lv = L.v;
}

typedef const __attribute__((address_space(1))) void* gas_p;
typedef __attribute__((address_space(3))) void* las_p;

// ws byte offsets
#define WH_OFF  0u
#define WL_OFF  (WH_OFF + 192u*1024u*2u)
#define FQH_OFF (WL_OFF + 192u*1024u*2u)
#define FQL_OFF (FQH_OFF + 2u*1024u*1024u)
#define FKH_OFF (FQL_OFF + 2u*1024u*1024u)
#define FKL_OFF (FKH_OFF + 2u*1024u*1024u)
#define VF_OFF  (FKL_OFF + 2u*1024u*1024u)
#define DD_OFF  (VF_OFF + 2u*1024u*1024u)          // fp32 [B][T] = 64 KB
#define PF_OFF  (DD_OFF + 8u*2048u*4u)             // bf16 quartets, 67 MB

// ---------------------------------------------------------------------------
// W -> fragment-coalesced bf16 (RNE).  Chunk kc (32 K-elems) of col-block
// nblk lives at nblk*16384 + kc*512 u16.
// ---------------------------------------------------------------------------
__global__ __launch_bounds__(128) void wsplit_kernel(
    const float* __restrict__ Wk, const float* __restrict__ Wq,
    const float* __restrict__ Wv, u16* __restrict__ FWH)
{
    const int n = blockIdx.x;                 // 0..191
    const int nblk = n >> 4, lr = n & 15;
    const float* src = (n < 64) ? (Wq + (long)n * 1024)
                     : (n < 128) ? (Wk + (long)(n - 64) * 1024)
                                 : (Wv + (long)(n - 128) * 1024);
    const int f = threadIdx.x;                // 0..127 fragment id
    const int kc = f >> 2, q = f & 3;
    const float4 f0 = *(const float4*)&src[kc * 32 + q * 8];
    const float4 f1 = *(const float4*)&src[kc * 32 + q * 8 + 4];
    const float vs[8] = {f0.x, f0.y, f0.z, f0.w, f1.x, f1.y, f1.z, f1.w};
    bf16x8 hv;
    #pragma unroll
    for (int j = 0; j < 8; ++j) hv[j] = (short)f2bf(vs[j]);
    const long o = ((long)(nblk * 32 + kc) * 64 + q * 16 + lr) * 8;
    *(bf16x8*)&FWH[o] = hv;
}

// ---------------------------------------------------------------------------
// qkv (r20 structure).  Counted-vmcnt DMA pipeline, 2-term split, phase K=64,
// 3 stages x 40 KB LDS, 5 DMA/wave/phase, boundary vmcnt(5) + bare s_barrier.
// Epilogue: Q/K hi only (full-bf16 QK dots, r25), V bf16.
// ---------------------------------------------------------------------------
__global__ __launch_bounds__(512, 2) void qkv_kernel(
    const float* __restrict__ idx, const u16* __restrict__ FWH,
    u16* __restrict__ FQH, u16* __restrict__ FKH, u16* __restrict__ VF)
{
    __shared__ __align__(16) char smem[3][40960];   // A 16KB + FWH 24KB
    const int tid = threadIdx.x;
    const int w = tid >> 6, lr = tid & 15, quad = (tid >> 4) & 3;
    const int lane = tid & 63;
    const int r0 = blockIdx.x * 64;
    const int b = r0 >> 11, t0 = r0 & 2047;
    const int m0 = (w & 1) * 32;
    const int nbb = (w >> 1) * 3;

    const float* asrc[2];
    int adst[2];
    #pragma unroll
    for (int j = 0; j < 2; ++j) {
        const int s = w * 2 + j;
        const int row = s * 4 + (lane >> 4);
        const int lc = (lane & 15) ^ (row & 7);
        asrc[j] = idx + (long)(r0 + row) * 1024 + lc * 4;
        adst[j] = s * 1024;
    }
    const u16* fsrc[3];
    int fdst[3];
    #pragma unroll
    for (int j = 0; j < 3; ++j) {
        const int seg = w * 3 + j;
        const int nblk = seg >> 1, kcl = seg & 1;
        fsrc[j] = FWH + (long)nblk * 16384 + kcl * 512 + lane * 8;
        fdst[j] = 16384 + seg * 1024;
    }

#define ISSUE(PH)                                                             \
    {                                                                         \
        const int nb_ = (PH) % 3;                                             \
        _Pragma("unroll")                                                     \
        for (int j = 0; j < 2; ++j)                                           \
            __builtin_amdgcn_global_load_lds((gas_p)(asrc[j] + (PH) * 64),    \
                (las_p)(smem[nb_] + adst[j]), 16, 0, 0);                      \
        _Pragma("unroll")                                                     \
        for (int j = 0; j < 3; ++j)                                           \
            __builtin_amdgcn_global_load_lds((gas_p)(fsrc[j] + (long)(PH) * 1024), \
                (las_p)(smem[nb_] + fdst[j]), 16, 0, 0);                      \
    }

#define COMPUTE(PH)                                                           \
    {                                                                         \
        const int nb_ = (PH) % 3;                                             \
        const float* A_ = (const float*)smem[nb_];                            \
        const u16* F_ = (const u16*)(smem[nb_] + 16384);                      \
        _Pragma("unroll")                                                     \
        for (int kc = 0; kc < 2; ++kc) {                                      \
            bf16x8 AH[2], AL[2];                                              \
            _Pragma("unroll")                                                 \
            for (int mi = 0; mi < 2; ++mi) {                                  \
                const int R = m0 + mi * 16 + lr;                              \
                const int c0 = (kc * 8 + quad * 2) ^ (lr & 7);                \
                const f32x4 x0 = *(const f32x4*)&A_[R * 64 + c0 * 4];         \
                const f32x4 x1 = *(const f32x4*)&A_[R * 64 + (c0 ^ 1) * 4];   \
                split8(x0, x1, &AH[mi], &AL[mi]);                             \
            }                                                                 \
            _Pragma("unroll")                                                 \
            for (int nf = 0; nf < 3; ++nf) {                                  \
                const int sb = (((nbb + nf) * 2 + kc)) * 512 + lane * 8;      \
                const bf16x8 bh = *(const bf16x8*)&F_[sb];                    \
                _Pragma("unroll")                                             \
                for (int mi = 0; mi < 2; ++mi) {                              \
                    f32x4 c = acc[mi][nf];                                    \
                    c = MFMA(AH[mi], bh, c);                                  \
                    c = MFMA(AL[mi], bh, c);                                  \
                    acc[mi][nf] = c;                                          \
                }                                                             \
            }                                                                 \
        }                                                                     \
    }

#define WAITV(N)                                                              \
    asm volatile("s_waitcnt vmcnt(" #N ")" ::: "memory");                     \
    __builtin_amdgcn_sched_barrier(0);                                        \
    __builtin_amdgcn_s_barrier();

    f32x4 acc[2][3] = {};

    ISSUE(0); ISSUE(1);
    WAITV(5)

    for (int ph = 0; ph < 14; ++ph) {
        ISSUE(ph + 2);
        __builtin_amdgcn_sched_barrier(0);
        COMPUTE(ph);
        WAITV(5)
    }
    COMPUTE(14);
    WAITV(0)
    COMPUTE(15);

#undef WAITV
#undef COMPUTE
#undef ISSUE

    #pragma unroll
    for (int mi = 0; mi < 2; ++mi) {
        const int tb = t0 + m0 + mi * 16 + quad * 4;
        const int tblk = (t0 + m0 + mi * 16) >> 4;
        #pragma unroll
        for (int nf = 0; nf < 3; ++nf) {
            const int n = (nbb + nf) * 16 + lr;
            const f32x4 a = acc[mi][nf];
            if (n < 128) {
                u16* Hd = (n < 64) ? FQH : FKH;
                const int h = n & 63;
                const int kc = h >> 5;
                const int lsub = 16 * ((h & 31) >> 3);
                const long base = ((long)(b * 128 + tblk) * 2 + kc) * 512 + (h & 7);
                #pragma unroll
                for (int r = 0; r < 4; ++r) {
                    const long o = base + (long)(quad * 4 + r + lsub) * 8;
                    Hd[o] = f2bf(a[r]);
                }
            } else {
                const int h = n - 128;
                const int hblk = h >> 4;
                #pragma unroll
                for (int r = 0; r < 4; ++r) {
                    const int t = tb + r;
                    const long o = ((long)(b * 4 + hblk) * 64 + (t >> 5)) * 512
                                 + (long)(16 * ((t & 31) >> 3) + (h & 15)) * 8 + (t & 7);
                    VF[o] = f2bf(a[r]);
                }
            }
        }
    }
}

// ---------------------------------------------------------------------------
// stats: D_s = sum_{t>=s} exp(q_t.k_s) AND stores P (masked, bf16) in
// QUARTET layout.  Full-bf16 QK: S = kh·qh, 2 MFMA per (sf,jt).
// Swapped MFMA: thread holds s = s0+sf*16+quad*4+r, t = jt*64+w*16+lr.
// Quartet -> uint2 store at [b][tblk=jt*4+w][sq=i*16+sf*4+quad][lr].
// Grid (80, B): s-tile i, t-chunk x of 8 jt (nc = (39-i)>>3).
// ---------------------------------------------------------------------------
__global__ __launch_bounds__(256, 4) void stats_kernel(
    const u16* __restrict__ FQH, const u16* __restrict__ FKH,
    u16* __restrict__ PF, float* __restrict__ D)
{
    __shared__ float red[4][64];
    const int tid = threadIdx.x;
    const int w = tid >> 6, lr = tid & 15, quad = (tid >> 4) & 3;
    const int lane = tid & 63;
    const int b = blockIdx.y;
    int x = blockIdx.x, i = 0;
    for (;;) { const int nc = (39 - i) >> 3; if (x < nc) break; x -= nc; ++i; }
    const int s0 = i * 64;
    const int jt0 = i + 8 * x, jt1 = min(jt0 + 8, 32);

    uint2* __restrict__ PQ = (uint2*)PF;

    // K hi frags hoisted (A-operand rows = s); sf = s-subtile 0..3.
    bf16x8 KH[4][2];
    #pragma unroll
    for (int sf = 0; sf < 4; ++sf) {
        const long kb = ((long)(b * 128 + i * 4 + sf) * 2) * 512 + lane * 8;
        KH[sf][0] = *(const bf16x8*)&FKH[kb];
        KH[sf][1] = *(const bf16x8*)&FKH[kb + 512];
    }

    float dsum[4][4] = {};
    for (int jt = jt0; jt < jt1; ++jt) {
        const long qb = ((long)(b * 128 + jt * 4 + w) * 2) * 512 + lane * 8;
        const bf16x8 qh0 = *(const bf16x8*)&FQH[qb];
        const bf16x8 qh1 = *(const bf16x8*)&FQH[qb + 512];
        const bool diag = (jt == i);
        const int t_sub = w * 16 + lr;
        const long tb_base = ((long)(b * 128 + jt * 4 + w)) * 512;
        #pragma unroll
        for (int sf = 0; sf < 4; ++sf) {
            f32x4 cc = {};
            cc = MFMA(KH[sf][0], qh0, cc);
            cc = MFMA(KH[sf][1], qh1, cc);

            u16 hq[4];
            #pragma unroll
            for (int r = 0; r < 4; ++r) {
                float ev = __expf(cc[r]);
                if (diag && (t_sub < sf * 16 + quad * 4 + r)) ev = 0.f;
                dsum[sf][r] += ev;
                hq[r] = f2bf(ev);
            }
            uint2 pk;
            pk.x = (unsigned)hq[0] | ((unsigned)hq[1] << 16);
            pk.y = (unsigned)hq[2] | ((unsigned)hq[3] << 16);
            PQ[(tb_base + i * 16 + sf * 4 + quad) * 16 + lr] = pk;
        }
    }

    #pragma unroll
    for (int sf = 0; sf < 4; ++sf)
        #pragma unroll
        for (int r = 0; r < 4; ++r) {
            float v = dsum[sf][r];
            v += __shfl_xor(v, 1);
            v += __shfl_xor(v, 2);
            v += __shfl_xor(v, 4);
            v += __shfl_xor(v, 8);
            dsum[sf][r] = v;
        }
    if (lr == 0) {
        #pragma unroll
        for (int sf = 0; sf < 4; ++sf)
            #pragma unroll
            for (int r = 0; r < 4; ++r)
                red[w][sf * 16 + quad * 4 + r] = dsum[sf][r];
    }
    __syncthreads();
    if (tid < 64)
        atomicAdd(&D[b * 2048 + s0 + tid],
                  red[0][tid] + red[1][tid] + red[2][tid] + red[3][tid]);
}

// ---------------------------------------------------------------------------
// out: streaming PV GEMM with inline 1/D scaling of P (vscale folded in).
// out[t][h] = sum_{s<=t} (P[t][s]/D_s) * V[s][h].  P A-frag assembled from 2
// adjacent quartets; its s-vector (js*64+kcp*32+g*8+j) matches D layout ->
// 16 rcp+mul per js.  Grid (80, B): t-tile i, s-chunk x; atomicAdd for i>=8.
// ---------------------------------------------------------------------------
__global__ __launch_bounds__(256, 4) void out_kernel(
    const u16* __restrict__ PF, const u16* __restrict__ VF,
    const float* __restrict__ D, float* __restrict__ out)
{
    const int tid = threadIdx.x;
    const int w = tid >> 6, lr = tid & 15, quad = (tid >> 4) & 3;
    const int lane = tid & 63;
    const int b = blockIdx.y;
    int x = blockIdx.x, i = 0;
    for (;;) { const int nc = (i + 8) >> 3; if (x < nc) break; x -= nc; ++i; }
    const int t0 = i * 64;
    const int js0 = 8 * x, js1 = min(8 * x + 8, i + 1);
    const int tblk = i * 4 + w;

    const uint2* __restrict__ PQ = (const uint2*)PF;
    const int g = lane >> 4, tr = lane & 15;
    const long tb_base = ((long)(b * 128 + tblk)) * 512;

    f32x4 oacc[4] = {};
    for (int js = js0; js < js1; ++js) {
        bf16x8 pa[2];
        #pragma unroll
        for (int kcp = 0; kcp < 2; ++kcp) {
            const long u = (tb_base + js * 16 + kcp * 8 + g * 2) * 16 + tr;
            const uint2 a0 = PQ[u];
            const uint2 a1 = PQ[u + 16];
            union { unsigned uu[4]; bf16x8 v; } P_;
            P_.uu[0] = a0.x; P_.uu[1] = a0.y; P_.uu[2] = a1.x; P_.uu[3] = a1.y;
            // scale by 1/D[s], s = js*64 + kcp*32 + g*8 + j
            const int sb = js * 64 + kcp * 32 + g * 8;
            const float4 d0 = *(const float4*)&D[b * 2048 + sb];
            const float4 d1 = *(const float4*)&D[b * 2048 + sb + 4];
            const float dv[8] = {d0.x, d0.y, d0.z, d0.w, d1.x, d1.y, d1.z, d1.w};
            bf16x8 sc;
            #pragma unroll
            for (int j = 0; j < 8; ++j)
                sc[j] = (short)f2bf(bf2f((u16)P_.v[j]) *
                                    __builtin_amdgcn_rcpf(dv[j]));
            pa[kcp] = sc;
        }
        #pragma unroll
        for (int nf = 0; nf < 4; ++nf) {
            const long vb = ((long)(b * 4 + nf) * 64 + 2 * js) * 512 + lane * 8;
            const bf16x8 v0 = *(const bf16x8*)&VF[vb];
            const bf16x8 v1 = *(const bf16x8*)&VF[vb + 512];
            oacc[nf] = MFMA(pa[0], v0, oacc[nf]);
            oacc[nf] = MFMA(pa[1], v1, oacc[nf]);
        }
    }

    const bool single = (i < 8);   // one chunk covers the whole row
    #pragma unroll
    for (int nf = 0; nf < 4; ++nf) {
        const int h = nf * 16 + lr;
        #pragma unroll
        for (int r = 0; r < 4; ++r) {
            const int t = t0 + w * 16 + quad * 4 + r;
            const long o = (long)(b * 2048 + t) * 64 + h;
            if (single) out[o] = oacc[nf][r];
            else        atomicAdd(&out[o], oacc[nf][r]);
        }
    }
}

extern "C" void kernel_launch(void* const* d_in, const int* in_sizes, int n_in,
                              void* d_out, int out_size, void* d_ws, size_t ws_size,
                              hipStream_t stream)
{
    const float* idx = (const float*)d_in[0];
    const float* Wk  = (const float*)d_in[1];
    const float* Wq  = (const float*)d_in[2];
    const float* Wv  = (const float*)d_in[3];
    char* ws = (char*)d_ws;
    float* out = (float*)d_out;

    u16* FWH = (u16*)(ws + WH_OFF);
    u16* FQH = (u16*)(ws + FQH_OFF);
    u16* FKH = (u16*)(ws + FKH_OFF);
    u16* VF  = (u16*)(ws + VF_OFF);
    float* Dp = (float*)(ws + DD_OFF);
    u16* PF  = (u16*)(ws + PF_OFF);

    hipMemsetAsync(out, 0, (size_t)8 * 2048 * 64 * sizeof(float), stream);
    hipMemsetAsync(Dp, 0, (size_t)8 * 2048 * sizeof(float), stream);

    wsplit_kernel<<<192, 128, 0, stream>>>(Wk, Wq, Wv, FWH);
    qkv_kernel<<<256, 512, 0, stream>>>(idx, FWH, FQH, FKH, VF);
    stats_kernel<<<dim3(80, 8), 256, 0, stream>>>(FQH, FKH, PF, Dp);
    out_kernel<<<dim3(80, 8), 256, 0, stream>>>(PF, VF, Dp, out);
}